// Round 9
// baseline (510.340 us; speedup 1.0000x reference)
//
#include <hip/hip_runtime.h>
#include <cstdint>
#include <cstddef>

#define B_  4
#define S_  2048
#define D_  1024
#define DK_ 128

typedef float  f32x4   __attribute__((ext_vector_type(4)));
typedef short  bf16x8s __attribute__((ext_vector_type(8)));
typedef unsigned int   u32;
typedef unsigned short u16;

// ----- bf16 helpers (manual RNE; values bounded, no NaN/Inf) -----
__device__ inline u32 rne(float f) {
    u32 u = __builtin_bit_cast(u32, f);
    return (u + 0x7fffu + ((u >> 16) & 1u)) >> 16;
}
__device__ inline u32 pack2(float a, float b) { return rne(a) | (rne(b) << 16); }
__device__ inline bf16x8s ldfrag(const u16* p) {
    union { uint4 u; bf16x8s v; } c;
    c.u = *(const uint4*)p;
    return c.v;
}
__device__ inline f32x4 MM(bf16x8s a, bf16x8s b, f32x4 c) {
    return __builtin_amdgcn_mfma_f32_16x16x32_bf16(a, b, c, 0, 0, 0);
}

// ---------------------------------------------------------------------------
// lengths[b] (bool mask may be 1-byte or int32; byte S_-1 discriminates)
// ---------------------------------------------------------------------------
__global__ void lengths_kernel(const uint8_t* __restrict__ mask,
                               int* __restrict__ lengths) {
    int b = blockIdx.x;
    bool is_i32 = (mask[S_ - 1] == 0);
    __shared__ int cnt[256];
    int t = threadIdx.x;
    int c = 0;
    for (int i = t; i < S_; i += 256) {
        int val;
        if (is_i32) val = ((const int*)mask)[b * S_ + i];
        else        val = mask[b * S_ + i];
        c += (val == 0) ? 1 : 0;
    }
    cnt[t] = c;
    __syncthreads();
    for (int s = 128; s > 0; s >>= 1) {
        if (t < s) cnt[t] += cnt[t + s];
        __syncthreads();
    }
    if (t == 0) lengths[b] = cnt[0];
}

// ---------------------------------------------------------------------------
// fp32 -> bf16, 4 per thread
// ---------------------------------------------------------------------------
__global__ __launch_bounds__(256) void tobf16_kernel(
    const float* __restrict__ in, u16* __restrict__ out) {
    size_t i = (size_t)blockIdx.x * 256 + threadIdx.x;
    float4 f = ((const float4*)in)[i];
    ushort4 o = { (u16)rne(f.x), (u16)rne(f.y), (u16)rne(f.z), (u16)rne(f.w) };
    ((ushort4*)out)[i] = o;
}

// ---------------------------------------------------------------------------
// transpose + bf16: W[K][N] fp32 -> WT[N][K] bf16
// ---------------------------------------------------------------------------
__global__ __launch_bounds__(256) void transpose_tobf16_kernel(
    const float* __restrict__ W, u16* __restrict__ T, int K, int N) {
    __shared__ float tl[32][33];
    const int t = threadIdx.x, tx = t & 31, ty = t >> 5;
    const int n0 = blockIdx.x * 32, k0 = blockIdx.y * 32;
#pragma unroll
    for (int i = 0; i < 4; ++i)
        tl[ty + i * 8][tx] = W[(size_t)(k0 + ty + i * 8) * N + n0 + tx];
    __syncthreads();
#pragma unroll
    for (int i = 0; i < 4; ++i) {
        float f = tl[tx][ty + i * 8];
        T[(size_t)(n0 + ty + i * 8) * K + k0 + tx] = (u16)rne(f);
    }
}

// ---------------------------------------------------------------------------
// NT-GEMM bf16: C[m][n] = (sum_k A[m][k]*B[n][k] + bias)*scale, C bf16.
// 4 waves 2x2, wave tile WM x WN, 16x16x32 MFMA, no LDS (L1/L2 reuse).
// ---------------------------------------------------------------------------
template<int BM, int BN, int WM, int WN>
__global__ __launch_bounds__(256) void gemm_nt(
    const u16* __restrict__ A, const u16* __restrict__ Bm,
    const float* __restrict__ bias_col, const float* __restrict__ bias_row,
    float scale, u16* __restrict__ C, int N, int K,
    size_t bStride, size_t cStride)
{
    constexpr int FM = WM / 16, FN = WN / 16;
    const int t = threadIdx.x, w = t >> 6, lane = t & 63;
    const int g = lane >> 4, c16 = lane & 15;
    const int m0 = blockIdx.y * BM + (w >> 1) * WM;
    const int n0 = blockIdx.x * BN + (w & 1) * WN;
    Bm += blockIdx.z * bStride;
    C  += blockIdx.z * cStride;

    f32x4 acc[FM][FN];
#pragma unroll
    for (int i = 0; i < FM; ++i)
#pragma unroll
        for (int j = 0; j < FN; ++j) acc[i][j] = (f32x4){0.f, 0.f, 0.f, 0.f};

    size_t aoff[FM], boff[FN];
#pragma unroll
    for (int i = 0; i < FM; ++i) aoff[i] = (size_t)(m0 + i * 16 + c16) * K + g * 8;
#pragma unroll
    for (int j = 0; j < FN; ++j) boff[j] = (size_t)(n0 + j * 16 + c16) * K + g * 8;

#pragma unroll 2
    for (int k0 = 0; k0 < K; k0 += 32) {
        bf16x8s a[FM], b[FN];
#pragma unroll
        for (int i = 0; i < FM; ++i) a[i] = ldfrag(A + aoff[i] + k0);
#pragma unroll
        for (int j = 0; j < FN; ++j) b[j] = ldfrag(Bm + boff[j] + k0);
#pragma unroll
        for (int i = 0; i < FM; ++i)
#pragma unroll
            for (int j = 0; j < FN; ++j)
                acc[i][j] = MM(a[i], b[j], acc[i][j]);
    }

#pragma unroll
    for (int i = 0; i < FM; ++i)
#pragma unroll
        for (int j = 0; j < FN; ++j) {
            const int n = n0 + j * 16 + c16;
            const float bc = bias_col ? bias_col[n] : 0.f;
#pragma unroll
            for (int r = 0; r < 4; ++r) {
                const int m = m0 + i * 16 + g * 4 + r;
                const float br = bias_row ? bias_row[m] : 0.f;
                float val = (acc[i][j][r] + bc + br) * scale;
                C[(size_t)m * N + n] = (u16)rne(val);
            }
        }
}

// ---------------------------------------------------------------------------
// vsumf[b][d] = sum_s VT[b][d][s]   (one wave per row)
// ---------------------------------------------------------------------------
__global__ __launch_bounds__(64) void vsum_rows_kernel(
    const u16* __restrict__ vt, float* __restrict__ vsumf) {
    const int blk = blockIdx.x;            // b*1024 + d
    const int lane = threadIdx.x;
    const u16* rr = vt + (size_t)blk * S_;
    float s = 0.f;
    for (int ch = lane; ch < S_ / 8; ch += 64) {
        union { uint4 u; u16 e[8]; } a;
        a.u = ((const uint4*)rr)[ch];
#pragma unroll
        for (int j = 0; j < 8; ++j)
            s += __builtin_bit_cast(float, (u32)a.e[j] << 16);
    }
#pragma unroll
    for (int off = 1; off < 64; off <<= 1) s += __shfl_xor(s, off);
    if (lane == 0) vsumf[blk] = s;
}

// ---------------------------------------------------------------------------
// MFMA flash attention, bf16. 1024 blocks, XCD swizzle (proven R8:
// FETCH 77->10.8MB, K/V L2-resident). 4 waves; wave w owns q rows
// r0+w*16..+15. Zero LDS; waves independent.
//
// R9: R8's counters (VGPR=68 vs ~150 needed to batch) proved the
// compiler's pressure-minimizing scheduler serializes the 16 loads
// (load->wait->use, ~16 x L2-latency per iter = the invariant 300us of
// R5-R8). Fix: sched_group_barrier pins a group of 16 VMEM_READ at the
// top of the body, then 8 MFMA (QK). Compiler then emits one counted
// vmcnt for the K batch; QK+softmax covers V latency.
//
// Swapped QK^T with PERMUTED K-row loads (see R4): S^T reg r of tile kt =
// key kb + g*8 + kt*4 + r -> P is directly the PV A-fragment octet.
// ---------------------------------------------------------------------------
__global__ __launch_bounds__(256, 3) void flash_mfma(
    const u16* __restrict__ qb, const u16* __restrict__ kbuf,
    const u16* __restrict__ vt, const float* __restrict__ vsumf,
    const int* __restrict__ lengths, float* __restrict__ out)
{
    const int lin     = (int)blockIdx.x;
    const int logical = (lin & 7) * 128 + (lin >> 3);
    const int tile    = 31 - (logical & 31);
    const int grp     = logical >> 5;
    const int b       = grp >> 3;
    const int slice   = grp & 7;

    const int r0 = tile * 64;
    const int t = threadIdx.x, w = t >> 6, lane = t & 63;
    const int g = lane >> 4, c16 = lane & 15;
    const int len = lengths[b];

    if (r0 >= len) {  // whole 64-row tile padded: rows = mean(v)
        const float inv = 1.0f / (float)S_;
        const float4* vs4 = (const float4*)(vsumf + (size_t)b * D_ + slice * 128);
        for (int idx = t; idx < 64 * 32; idx += 256) {  // 64 rows x 32 float4
            int rr = idx >> 5, c4 = idx & 31;
            float4 vv = vs4[c4];
            float4 o = { vv.x * inv, vv.y * inv, vv.z * inv, vv.w * inv };
            ((float4*)(out + ((size_t)(b * S_ + r0 + rr)) * D_ + slice * 128))[c4] = o;
        }
        return;
    }

    const int qr = r0 + w * 16;       // wave's q-row base
    const int qg = qr + c16;          // this lane's softmax q row

    // Q B-fragments (hoisted)
    bf16x8s Q[4];
    {
        const size_t qrow = (size_t)(b * S_ + qr + c16) * DK_;
#pragma unroll
        for (int dt = 0; dt < 4; ++dt)
            Q[dt] = ldfrag(qb + qrow + dt * 32 + g * 8);
    }

    f32x4 acc[8];
#pragma unroll
    for (int i = 0; i < 8; ++i) acc[i] = (f32x4){0.f, 0.f, 0.f, 0.f};
    float m_r = -3.0e38f, l_r = 0.f;

    const int keyloc0 = ((c16 >> 2) << 3) + (c16 & 3);  // permuted key row
    const int kmax_w = (qr >= len) ? -1 : min(qr + 15, len - 1);

    for (int kb = 0; kb <= kmax_w; kb += 32) {
        // ---- issue K batch (8 frags), then V batch (8 frags) ----
        bf16x8s Kf[8];
        const size_t krow = (size_t)(b * S_ + kb + keyloc0) * DK_;
#pragma unroll
        for (int dt = 0; dt < 4; ++dt) {
            Kf[dt]     = ldfrag(kbuf + krow + dt * 32 + g * 8);
            Kf[4 + dt] = ldfrag(kbuf + krow + 4 * DK_ + dt * 32 + g * 8);
        }
        bf16x8s Vf[8];
        const size_t vbase = (size_t)(b * D_ + slice * 128 + c16) * S_ + kb + g * 8;
#pragma unroll
        for (int cg = 0; cg < 8; ++cg)
            Vf[cg] = ldfrag(vt + vbase + (size_t)cg * 16 * S_);

        // R9: force the scheduler to CLUSTER all 16 loads here (group 1),
        // then place the 8 QK MFMAs (group 2). Overrides the pressure-
        // minimizing serialization seen in R5-R8 (VGPR=68 tell).
        __builtin_amdgcn_sched_group_barrier(0x020, 16, 0);  // VMEM_READ x16
        __builtin_amdgcn_sched_group_barrier(0x008, 8, 0);   // MFMA x8 (QK)

        // ---- S^T = K . Q^T ----
        f32x4 sT[2];
#pragma unroll
        for (int kt = 0; kt < 2; ++kt) {
            f32x4 s = (f32x4){0.f, 0.f, 0.f, 0.f};
#pragma unroll
            for (int dt = 0; dt < 4; ++dt)
                s = MM(Kf[kt * 4 + dt], Q[dt], s);
            sT[kt] = s;
        }
        // ---- causal mask: reg r of tile kt = key kb + g*8 + kt*4 + r ----
#pragma unroll
        for (int kt = 0; kt < 2; ++kt)
#pragma unroll
            for (int r = 0; r < 4; ++r) {
                int key = kb + g * 8 + kt * 4 + r;
                if (key > qg) sT[kt][r] = -3.0e38f;
            }
        // ---- online softmax over key axis (per q row = lane c16) ----
        float cmax = sT[0][0];
#pragma unroll
        for (int r = 1; r < 4; ++r) cmax = fmaxf(cmax, sT[0][r]);
#pragma unroll
        for (int r = 0; r < 4; ++r) cmax = fmaxf(cmax, sT[1][r]);
        cmax = fmaxf(cmax, __shfl_xor(cmax, 16));
        cmax = fmaxf(cmax, __shfl_xor(cmax, 32));

        const bool noresc = __all(cmax <= m_r + 8.0f);  // defer-rescale (T13)
        float m_new = m_r, sc = 1.0f;
        if (!noresc) {
            m_new = fmaxf(m_r, cmax);
            sc = __expf(m_r - m_new);
        }

        float p[2][4];
        float rs = 0.f;
#pragma unroll
        for (int kt = 0; kt < 2; ++kt)
#pragma unroll
            for (int r = 0; r < 4; ++r) {
                p[kt][r] = __expf(sT[kt][r] - m_new);
                rs += p[kt][r];
            }
        rs += __shfl_xor(rs, 16);
        rs += __shfl_xor(rs, 32);

        if (!noresc) {
            // acc q rows are REG-indexed (row = g*4+r): per-row sc
            float scr0 = __shfl(sc, g * 4 + 0, 16);
            float scr1 = __shfl(sc, g * 4 + 1, 16);
            float scr2 = __shfl(sc, g * 4 + 2, 16);
            float scr3 = __shfl(sc, g * 4 + 3, 16);
            f32x4 scv = { scr0, scr1, scr2, scr3 };
#pragma unroll
            for (int i = 0; i < 8; ++i) acc[i] *= scv;
            l_r = l_r * sc + rs;
            m_r = m_new;
        } else {
            l_r += rs;
        }

        // ---- pack P into A-fragment octet (lane-local) ----
        union { u32 wrd[4]; bf16x8s v; } pa;
        pa.wrd[0] = pack2(p[0][0], p[0][1]);
        pa.wrd[1] = pack2(p[0][2], p[0][3]);
        pa.wrd[2] = pack2(p[1][0], p[1][1]);
        pa.wrd[3] = pack2(p[1][2], p[1][3]);

        // ---- PV over this block's 128-col slice ----
#pragma unroll
        for (int cg = 0; cg < 8; ++cg)
            acc[cg] = MM(pa.v, Vf[cg], acc[cg]);
    }

    // ---- epilogue: C rows = q (reg axis), cols = d (lane axis) ----
    const float linv = 1.0f / l_r;
    float iv[4];
    bool valid[4];
#pragma unroll
    for (int r = 0; r < 4; ++r) {
        const int row = g * 4 + r;
        iv[r] = __shfl(linv, row, 16);
        valid[r] = (qr + row) < len;
    }
    const float invS = 1.0f / (float)S_;
#pragma unroll
    for (int cg = 0; cg < 8; ++cg) {
        const int d = slice * 128 + cg * 16 + c16;
        const float vsv = vsumf[(size_t)b * D_ + d] * invS;
#pragma unroll
        for (int r = 0; r < 4; ++r) {
            const int rowg = qr + g * 4 + r;
            const float val = valid[r] ? acc[cg][r] * iv[r] : vsv;
            out[((size_t)(b * S_ + rowg)) * D_ + d] = val;
        }
    }
}

// ---------------------------------------------------------------------------
extern "C" void kernel_launch(void* const* d_in, const int* in_sizes, int n_in,
                              void* d_out, int out_size, void* d_ws, size_t ws_size,
                              hipStream_t stream) {
    const float*   x    = (const float*)d_in[0];
    const uint8_t* mask = (const uint8_t*)d_in[1];
    const float*   Wq   = (const float*)d_in[2];
    const float*   bq   = (const float*)d_in[3];
    const float*   Wk   = (const float*)d_in[4];
    const float*   bk   = (const float*)d_in[5];
    const float*   Wv   = (const float*)d_in[6];
    const float*   bv   = (const float*)d_in[7];
    float* out = (float*)d_out;

    // workspace (u16 planes), total ~40.4 MB
    u16* u = (u16*)d_ws;
    u16* x_bf = u;                    u += (size_t)8192 * 1024;
    u16* wqt  = u;                    u += (size_t)128 * 1024;
    u16* wkt  = u;                    u += (size_t)128 * 1024;
    u16* wvt  = u;                    u += (size_t)1024 * 1024;
    u16* qb   = u;                    u += (size_t)8192 * 128;
    u16* kbuf = u;                    u += (size_t)8192 * 128;
    u16* vt   = u;                    u += (size_t)B_ * 1024 * 2048;
    float* vsumf = (float*)u;
    int* lengths = (int*)(vsumf + B_ * D_);

    const float SCALE = 0.08838834764831845f;  // 1/sqrt(128)

    lengths_kernel<<<dim3(B_), dim3(256), 0, stream>>>(mask, lengths);
    tobf16_kernel<<<dim3(8192), dim3(256), 0, stream>>>(x, x_bf);
    transpose_tobf16_kernel<<<dim3(4, 32), dim3(256), 0, stream>>>(Wq, wqt, 1024, 128);
    transpose_tobf16_kernel<<<dim3(4, 32), dim3(256), 0, stream>>>(Wk, wkt, 1024, 128);
    transpose_tobf16_kernel<<<dim3(32, 32), dim3(256), 0, stream>>>(Wv, wvt, 1024, 1024);

    // q = (x@Wq + bq)*scale ; k = x@Wk + bk    ([8192][128] bf16)
    gemm_nt<64, 64, 32, 32><<<dim3(2, 128, 1), dim3(256), 0, stream>>>(
        x_bf, wqt, bq, nullptr, SCALE, qb, 128, 1024, 0, 0);
    gemm_nt<64, 64, 32, 32><<<dim3(2, 128, 1), dim3(256), 0, stream>>>(
        x_bf, wkt, bk, nullptr, 1.0f, kbuf, 128, 1024, 0, 0);
    // VT[b] = Wv^T @ x[b]^T + bv[d]   ([1024 d][2048 tok] bf16, per batch)
    gemm_nt<128, 128, 64, 64><<<dim3(16, 8, B_), dim3(256), 0, stream>>>(
        wvt, x_bf, nullptr, bv, 1.0f, vt, 2048, 1024,
        (size_t)2048 * 1024, (size_t)1024 * 2048);

    vsum_rows_kernel<<<dim3(B_ * D_), dim3(64), 0, stream>>>(vt, vsumf);

    flash_mfma<<<dim3(1024), dim3(256), 0, stream>>>(
        qb, kbuf, vt, vsumf, lengths, out);
}

// Round 10
// 304.648 us; speedup vs baseline: 1.6752x; 1.6752x over previous
//
#include <hip/hip_runtime.h>
#include <cstdint>
#include <cstddef>

#define B_  4
#define S_  2048
#define D_  1024
#define DK_ 128

typedef float  f32x4   __attribute__((ext_vector_type(4)));
typedef short  bf16x8s __attribute__((ext_vector_type(8)));
typedef unsigned int   u32;
typedef unsigned short u16;

// ----- bf16 helpers (manual RNE; values bounded, no NaN/Inf) -----
__device__ inline u32 rne(float f) {
    u32 u = __builtin_bit_cast(u32, f);
    return (u + 0x7fffu + ((u >> 16) & 1u)) >> 16;
}
__device__ inline u32 pack2(float a, float b) { return rne(a) | (rne(b) << 16); }
__device__ inline bf16x8s ldfrag(const u16* p) {
    union { uint4 u; bf16x8s v; } c;
    c.u = *(const uint4*)p;
    return c.v;
}
__device__ inline f32x4 MM(bf16x8s a, bf16x8s b, f32x4 c) {
    return __builtin_amdgcn_mfma_f32_16x16x32_bf16(a, b, c, 0, 0, 0);
}
// async global(16B/lane) -> LDS(wave-uniform base + lane*16)
__device__ inline void gload_lds16(const void* gsrc, void* ldst) {
    __builtin_amdgcn_global_load_lds(
        (const __attribute__((address_space(1))) unsigned int*)gsrc,
        (__attribute__((address_space(3))) unsigned int*)ldst, 16, 0, 0);
}

// ---------------------------------------------------------------------------
// lengths[b] (bool mask may be 1-byte or int32; byte S_-1 discriminates)
// ---------------------------------------------------------------------------
__global__ void lengths_kernel(const uint8_t* __restrict__ mask,
                               int* __restrict__ lengths) {
    int b = blockIdx.x;
    bool is_i32 = (mask[S_ - 1] == 0);
    __shared__ int cnt[256];
    int t = threadIdx.x;
    int c = 0;
    for (int i = t; i < S_; i += 256) {
        int val;
        if (is_i32) val = ((const int*)mask)[b * S_ + i];
        else        val = mask[b * S_ + i];
        c += (val == 0) ? 1 : 0;
    }
    cnt[t] = c;
    __syncthreads();
    for (int s = 128; s > 0; s >>= 1) {
        if (t < s) cnt[t] += cnt[t + s];
        __syncthreads();
    }
    if (t == 0) lengths[b] = cnt[0];
}

// ---------------------------------------------------------------------------
// fp32 -> bf16, 4 per thread
// ---------------------------------------------------------------------------
__global__ __launch_bounds__(256) void tobf16_kernel(
    const float* __restrict__ in, u16* __restrict__ out) {
    size_t i = (size_t)blockIdx.x * 256 + threadIdx.x;
    float4 f = ((const float4*)in)[i];
    ushort4 o = { (u16)rne(f.x), (u16)rne(f.y), (u16)rne(f.z), (u16)rne(f.w) };
    ((ushort4*)out)[i] = o;
}

// ---------------------------------------------------------------------------
// transpose + bf16: W[K][N] fp32 -> WT[N][K] bf16
// ---------------------------------------------------------------------------
__global__ __launch_bounds__(256) void transpose_tobf16_kernel(
    const float* __restrict__ W, u16* __restrict__ T, int K, int N) {
    __shared__ float tl[32][33];
    const int t = threadIdx.x, tx = t & 31, ty = t >> 5;
    const int n0 = blockIdx.x * 32, k0 = blockIdx.y * 32;
#pragma unroll
    for (int i = 0; i < 4; ++i)
        tl[ty + i * 8][tx] = W[(size_t)(k0 + ty + i * 8) * N + n0 + tx];
    __syncthreads();
#pragma unroll
    for (int i = 0; i < 4; ++i) {
        float f = tl[tx][ty + i * 8];
        T[(size_t)(n0 + ty + i * 8) * K + k0 + tx] = (u16)rne(f);
    }
}

// ---------------------------------------------------------------------------
// NT-GEMM bf16: C[m][n] = (sum_k A[m][k]*B[n][k] + bias)*scale, C bf16.
// 4 waves 2x2, wave tile WM x WN, 16x16x32 MFMA, no LDS (L1/L2 reuse).
// ---------------------------------------------------------------------------
template<int BM, int BN, int WM, int WN>
__global__ __launch_bounds__(256) void gemm_nt(
    const u16* __restrict__ A, const u16* __restrict__ Bm,
    const float* __restrict__ bias_col, const float* __restrict__ bias_row,
    float scale, u16* __restrict__ C, int N, int K,
    size_t bStride, size_t cStride)
{
    constexpr int FM = WM / 16, FN = WN / 16;
    const int t = threadIdx.x, w = t >> 6, lane = t & 63;
    const int g = lane >> 4, c16 = lane & 15;
    const int m0 = blockIdx.y * BM + (w >> 1) * WM;
    const int n0 = blockIdx.x * BN + (w & 1) * WN;
    Bm += blockIdx.z * bStride;
    C  += blockIdx.z * cStride;

    f32x4 acc[FM][FN];
#pragma unroll
    for (int i = 0; i < FM; ++i)
#pragma unroll
        for (int j = 0; j < FN; ++j) acc[i][j] = (f32x4){0.f, 0.f, 0.f, 0.f};

    size_t aoff[FM], boff[FN];
#pragma unroll
    for (int i = 0; i < FM; ++i) aoff[i] = (size_t)(m0 + i * 16 + c16) * K + g * 8;
#pragma unroll
    for (int j = 0; j < FN; ++j) boff[j] = (size_t)(n0 + j * 16 + c16) * K + g * 8;

#pragma unroll 2
    for (int k0 = 0; k0 < K; k0 += 32) {
        bf16x8s a[FM], b[FN];
#pragma unroll
        for (int i = 0; i < FM; ++i) a[i] = ldfrag(A + aoff[i] + k0);
#pragma unroll
        for (int j = 0; j < FN; ++j) b[j] = ldfrag(Bm + boff[j] + k0);
#pragma unroll
        for (int i = 0; i < FM; ++i)
#pragma unroll
            for (int j = 0; j < FN; ++j)
                acc[i][j] = MM(a[i], b[j], acc[i][j]);
    }

#pragma unroll
    for (int i = 0; i < FM; ++i)
#pragma unroll
        for (int j = 0; j < FN; ++j) {
            const int n = n0 + j * 16 + c16;
            const float bc = bias_col ? bias_col[n] : 0.f;
#pragma unroll
            for (int r = 0; r < 4; ++r) {
                const int m = m0 + i * 16 + g * 4 + r;
                const float br = bias_row ? bias_row[m] : 0.f;
                float val = (acc[i][j][r] + bc + br) * scale;
                C[(size_t)m * N + n] = (u16)rne(val);
            }
        }
}

// ---------------------------------------------------------------------------
// vsumf[b][d] = sum_s VT[b][d][s]   (one wave per row)
// ---------------------------------------------------------------------------
__global__ __launch_bounds__(64) void vsum_rows_kernel(
    const u16* __restrict__ vt, float* __restrict__ vsumf) {
    const int blk = blockIdx.x;            // b*1024 + d
    const int lane = threadIdx.x;
    const u16* rr = vt + (size_t)blk * S_;
    float s = 0.f;
    for (int ch = lane; ch < S_ / 8; ch += 64) {
        union { uint4 u; u16 e[8]; } a;
        a.u = ((const uint4*)rr)[ch];
#pragma unroll
        for (int j = 0; j < 8; ++j)
            s += __builtin_bit_cast(float, (u32)a.e[j] << 16);
    }
#pragma unroll
    for (int off = 1; off < 64; off <<= 1) s += __shfl_xor(s, off);
    if (lane == 0) vsumf[blk] = s;
}

// ---------------------------------------------------------------------------
// MFMA flash attention, bf16, LDS-STAGED (R10).
// 1024 blocks, XCD swizzle (proven: FETCH 77->10.8MB). 4 waves; wave w owns
// q rows r0+w*16..+15; block slice = 128 D-cols.
//
// R5-R9 post-mortem: per-wave direct loads were serialized by the compiler
// (load->wait->use, VGPR tell: 68-128) -> critical path = longest wave
// (~66 chunks x ~8k cy). Also all 4 waves loaded IDENTICAL K and V frags.
// R10: stage K(8KB)+V(8KB) per chunk into LDS cooperatively with
// global_load_lds (async, coalesced, once per block), double-buffered;
// compute reads ds_read_b128. One __syncthreads per chunk (its implicit
// vmcnt(0) drain completes the stage).
//
// Swizzles (rule #21: linear LDS dest + inverse-swz SOURCE + swz on READ):
//  K tile [32 rows][256B]: seg(16B) ^= (row&3)|(((row>>3)&3)<<2)
//    -> read seg' = (dt*4+g)^c16 : 16 distinct segs per 16-lane phase, 0-way.
//  V tile [128 rows][64B]: seg ^= (row>>1)&3 -> 2-way (free).
//
// Swapped QK^T with PERMUTED K-rows (R4): S^T reg r of tile kt = key
// kb + g*8 + kt*4 + r -> P is directly the PV A-fragment octet.
// ---------------------------------------------------------------------------
#define KVB 32

__global__ __launch_bounds__(256, 3) void flash_mfma(
    const u16* __restrict__ qb, const u16* __restrict__ kbuf,
    const u16* __restrict__ vt, const float* __restrict__ vsumf,
    const int* __restrict__ lengths, float* __restrict__ out)
{
    const int lin     = (int)blockIdx.x;
    const int logical = (lin & 7) * 128 + (lin >> 3);
    const int tile    = 31 - (logical & 31);
    const int grp     = logical >> 5;
    const int b       = grp >> 3;
    const int slice   = grp & 7;

    const int r0 = tile * 64;
    const int t = threadIdx.x, w = t >> 6, lane = t & 63;
    const int g = lane >> 4, c16 = lane & 15;
    const int len = lengths[b];

    if (r0 >= len) {  // whole 64-row tile padded: rows = mean(v)
        const float inv = 1.0f / (float)S_;
        const float4* vs4 = (const float4*)(vsumf + (size_t)b * D_ + slice * 128);
        for (int idx = t; idx < 64 * 32; idx += 256) {  // 64 rows x 32 float4
            int rr = idx >> 5, c4 = idx & 31;
            float4 vv = vs4[c4];
            float4 o = { vv.x * inv, vv.y * inv, vv.z * inv, vv.w * inv };
            ((float4*)(out + ((size_t)(b * S_ + r0 + rr)) * D_ + slice * 128))[c4] = o;
        }
        return;
    }

    __shared__ alignas(16) u16 ksm[2][KVB * DK_];   // 2 x 8KB
    __shared__ alignas(16) u16 vsm[2][128 * KVB];   // 2 x 8KB

    const int qr = r0 + w * 16;       // wave's q-row base
    const int qg = qr + c16;          // this lane's softmax q row

    // Q B-fragments (hoisted)
    bf16x8s Q[4];
    {
        const size_t qrow = (size_t)(b * S_ + qr + c16) * DK_;
#pragma unroll
        for (int dt = 0; dt < 4; ++dt)
            Q[dt] = ldfrag(qb + qrow + dt * 32 + g * 8);
    }

    f32x4 acc[8];
#pragma unroll
    for (int i = 0; i < 8; ++i) acc[i] = (f32x4){0.f, 0.f, 0.f, 0.f};
    float m_r = -3.0e38f, l_r = 0.f;

    const int keyloc0 = ((c16 >> 2) << 3) + (c16 & 3);  // permuted key row
    const int kmax_w  = (qr >= len) ? -1 : min(qr + 15, len - 1);
    const int kmaxblk = min(r0 + 63, len - 1);          // block-uniform
    const int nt      = kmaxblk / KVB + 1;              // chunks (uniform)

    // ---- cooperative async stage of chunk kb2 into buffer bufi ----
    auto stage = [&](int bufi, int kb2) {
#pragma unroll
        for (int i = 0; i < 2; ++i) {              // K: 512 slots of 16B
            const int slot = i * 256 + w * 64 + lane;
            const int row  = slot >> 4;            // 0..31
            const int segd = (slot & 15) ^ ((row & 3) | (((row >> 3) & 3) << 2));
            const u16* gsrc = kbuf + (size_t)(b * S_ + kb2 + row) * DK_ + segd * 8;
            gload_lds16(gsrc, &ksm[bufi][(size_t)(i * 256 + w * 64) * 8]);
        }
#pragma unroll
        for (int i = 0; i < 2; ++i) {              // V: 512 slots of 16B
            const int slot = i * 256 + w * 64 + lane;
            const int row  = slot >> 2;            // 0..127
            const int segd = (slot & 3) ^ ((row >> 1) & 3);
            const u16* gsrc = vt + (size_t)(b * D_ + slice * 128 + row) * S_
                                 + kb2 + segd * 8;
            gload_lds16(gsrc, &vsm[bufi][(size_t)(i * 256 + w * 64) * 8]);
        }
    };

    stage(0, 0);
    __syncthreads();   // implicit vmcnt(0) drain completes stage 0

    for (int ti = 0; ti < nt; ++ti) {
        const int kb  = ti * KVB;
        const int cur = ti & 1;
        if (ti + 1 < nt) stage(cur ^ 1, kb + KVB);   // async prefetch next

        if (kb <= kmax_w) {
            // ---- S^T = K . Q^T from LDS (swizzled reads, 0-conflict) ----
            f32x4 sT[2];
#pragma unroll
            for (int kt = 0; kt < 2; ++kt) {
                f32x4 s = (f32x4){0.f, 0.f, 0.f, 0.f};
#pragma unroll
                for (int dt = 0; dt < 4; ++dt) {
                    const bf16x8s kf = *(const bf16x8s*)&ksm[cur]
                        [(keyloc0 + kt * 4) * DK_ + (((dt * 4 + g) ^ c16) * 8)];
                    s = MM(kf, Q[dt], s);
                }
                sT[kt] = s;
            }
            // ---- causal mask: reg r of tile kt = key kb + g*8 + kt*4 + r ----
#pragma unroll
            for (int kt = 0; kt < 2; ++kt)
#pragma unroll
                for (int r = 0; r < 4; ++r) {
                    int key = kb + g * 8 + kt * 4 + r;
                    if (key > qg) sT[kt][r] = -3.0e38f;
                }
            // ---- online softmax over key axis (per q row = lane c16) ----
            float cmax = sT[0][0];
#pragma unroll
            for (int r = 1; r < 4; ++r) cmax = fmaxf(cmax, sT[0][r]);
#pragma unroll
            for (int r = 0; r < 4; ++r) cmax = fmaxf(cmax, sT[1][r]);
            cmax = fmaxf(cmax, __shfl_xor(cmax, 16));
            cmax = fmaxf(cmax, __shfl_xor(cmax, 32));

            const bool noresc = __all(cmax <= m_r + 8.0f);  // defer-rescale T13
            float m_new = m_r, sc = 1.0f;
            if (!noresc) {
                m_new = fmaxf(m_r, cmax);
                sc = __expf(m_r - m_new);
            }

            float p[2][4];
            float rs = 0.f;
#pragma unroll
            for (int kt = 0; kt < 2; ++kt)
#pragma unroll
                for (int r = 0; r < 4; ++r) {
                    p[kt][r] = __expf(sT[kt][r] - m_new);
                    rs += p[kt][r];
                }
            rs += __shfl_xor(rs, 16);
            rs += __shfl_xor(rs, 32);

            if (!noresc) {
                // acc q rows are REG-indexed (row = g*4+r): per-row sc
                float scr0 = __shfl(sc, g * 4 + 0, 16);
                float scr1 = __shfl(sc, g * 4 + 1, 16);
                float scr2 = __shfl(sc, g * 4 + 2, 16);
                float scr3 = __shfl(sc, g * 4 + 3, 16);
                f32x4 scv = { scr0, scr1, scr2, scr3 };
#pragma unroll
                for (int i = 0; i < 8; ++i) acc[i] *= scv;
                l_r = l_r * sc + rs;
                m_r = m_new;
            } else {
                l_r += rs;
            }

            // ---- pack P into A-fragment octet (lane-local) ----
            union { u32 wrd[4]; bf16x8s v; } pa;
            pa.wrd[0] = pack2(p[0][0], p[0][1]);
            pa.wrd[1] = pack2(p[0][2], p[0][3]);
            pa.wrd[2] = pack2(p[1][0], p[1][1]);
            pa.wrd[3] = pack2(p[1][2], p[1][3]);

            // ---- PV from LDS (swizzled reads, 2-way = free) ----
#pragma unroll
            for (int cg = 0; cg < 8; ++cg) {
                const bf16x8s vf = *(const bf16x8s*)&vsm[cur]
                    [(cg * 16 + c16) * KVB + ((g ^ ((c16 >> 1) & 3)) * 8)];
                acc[cg] = MM(pa.v, vf, acc[cg]);
            }
        }

        __syncthreads();  // drains stage vmcnt; next buffer ready, cur free
    }

    // ---- epilogue: C rows = q (reg axis), cols = d (lane axis) ----
    const float linv = 1.0f / l_r;
    float iv[4];
    bool valid[4];
#pragma unroll
    for (int r = 0; r < 4; ++r) {
        const int row = g * 4 + r;
        iv[r] = __shfl(linv, row, 16);
        valid[r] = (qr + row) < len;
    }
    const float invS = 1.0f / (float)S_;
#pragma unroll
    for (int cg = 0; cg < 8; ++cg) {
        const int d = slice * 128 + cg * 16 + c16;
        const float vsv = vsumf[(size_t)b * D_ + d] * invS;
#pragma unroll
        for (int r = 0; r < 4; ++r) {
            const int rowg = qr + g * 4 + r;
            const float val = valid[r] ? acc[cg][r] * iv[r] : vsv;
            out[((size_t)(b * S_ + rowg)) * D_ + d] = val;
        }
    }
}

// ---------------------------------------------------------------------------
extern "C" void kernel_launch(void* const* d_in, const int* in_sizes, int n_in,
                              void* d_out, int out_size, void* d_ws, size_t ws_size,
                              hipStream_t stream) {
    const float*   x    = (const float*)d_in[0];
    const uint8_t* mask = (const uint8_t*)d_in[1];
    const float*   Wq   = (const float*)d_in[2];
    const float*   bq   = (const float*)d_in[3];
    const float*   Wk   = (const float*)d_in[4];
    const float*   bk   = (const float*)d_in[5];
    const float*   Wv   = (const float*)d_in[6];
    const float*   bv   = (const float*)d_in[7];
    float* out = (float*)d_out;

    // workspace (u16 planes), total ~40.4 MB
    u16* u = (u16*)d_ws;
    u16* x_bf = u;                    u += (size_t)8192 * 1024;
    u16* wqt  = u;                    u += (size_t)128 * 1024;
    u16* wkt  = u;                    u += (size_t)128 * 1024;
    u16* wvt  = u;                    u += (size_t)1024 * 1024;
    u16* qb   = u;                    u += (size_t)8192 * 128;
    u16* kbuf = u;                    u += (size_t)8192 * 128;
    u16* vt   = u;                    u += (size_t)B_ * 1024 * 2048;
    float* vsumf = (float*)u;
    int* lengths = (int*)(vsumf + B_ * D_);

    const float SCALE = 0.08838834764831845f;  // 1/sqrt(128)

    lengths_kernel<<<dim3(B_), dim3(256), 0, stream>>>(mask, lengths);
    tobf16_kernel<<<dim3(8192), dim3(256), 0, stream>>>(x, x_bf);
    transpose_tobf16_kernel<<<dim3(4, 32), dim3(256), 0, stream>>>(Wq, wqt, 1024, 128);
    transpose_tobf16_kernel<<<dim3(4, 32), dim3(256), 0, stream>>>(Wk, wkt, 1024, 128);
    transpose_tobf16_kernel<<<dim3(32, 32), dim3(256), 0, stream>>>(Wv, wvt, 1024, 1024);

    // q = (x@Wq + bq)*scale ; k = x@Wk + bk    ([8192][128] bf16)
    gemm_nt<64, 64, 32, 32><<<dim3(2, 128, 1), dim3(256), 0, stream>>>(
        x_bf, wqt, bq, nullptr, SCALE, qb, 128, 1024, 0, 0);
    gemm_nt<64, 64, 32, 32><<<dim3(2, 128, 1), dim3(256), 0, stream>>>(
        x_bf, wkt, bk, nullptr, 1.0f, kbuf, 128, 1024, 0, 0);
    // VT[b] = Wv^T @ x[b]^T + bv[d]   ([1024 d][2048 tok] bf16, per batch)
    gemm_nt<128, 128, 64, 64><<<dim3(16, 8, B_), dim3(256), 0, stream>>>(
        wvt, x_bf, nullptr, bv, 1.0f, vt, 2048, 1024,
        (size_t)2048 * 1024, (size_t)1024 * 2048);

    vsum_rows_kernel<<<dim3(B_ * D_), dim3(64), 0, stream>>>(vt, vsumf);

    flash_mfma<<<dim3(1024), dim3(256), 0, stream>>>(
        qb, kbuf, vt, vsumf, lengths, out);
}

// Round 11
// 244.769 us; speedup vs baseline: 2.0850x; 1.2446x over previous
//
#include <hip/hip_runtime.h>
#include <cstdint>
#include <cstddef>

#define B_  4
#define S_  2048
#define D_  1024
#define DK_ 128

typedef float  f32x4   __attribute__((ext_vector_type(4)));
typedef short  bf16x8s __attribute__((ext_vector_type(8)));
typedef unsigned int   u32;
typedef unsigned short u16;

// ----- bf16 helpers (manual RNE; values bounded, no NaN/Inf) -----
__device__ inline u32 rne(float f) {
    u32 u = __builtin_bit_cast(u32, f);
    return (u + 0x7fffu + ((u >> 16) & 1u)) >> 16;
}
__device__ inline u32 pack2(float a, float b) { return rne(a) | (rne(b) << 16); }
__device__ inline bf16x8s ldfrag(const u16* p) {
    union { uint4 u; bf16x8s v; } c;
    c.u = *(const uint4*)p;
    return c.v;
}
__device__ inline f32x4 MM(bf16x8s a, bf16x8s b, f32x4 c) {
    return __builtin_amdgcn_mfma_f32_16x16x32_bf16(a, b, c, 0, 0, 0);
}
// async global(16B/lane) -> LDS(wave-uniform base + lane*16)
__device__ inline void gload_lds16(const void* gsrc, void* ldst) {
    __builtin_amdgcn_global_load_lds(
        (const __attribute__((address_space(1))) unsigned int*)gsrc,
        (__attribute__((address_space(3))) unsigned int*)ldst, 16, 0, 0);
}

// ---------------------------------------------------------------------------
// lengths[b] (bool mask may be 1-byte or int32; byte S_-1 discriminates)
// ---------------------------------------------------------------------------
__global__ void lengths_kernel(const uint8_t* __restrict__ mask,
                               int* __restrict__ lengths) {
    int b = blockIdx.x;
    bool is_i32 = (mask[S_ - 1] == 0);
    __shared__ int cnt[256];
    int t = threadIdx.x;
    int c = 0;
    for (int i = t; i < S_; i += 256) {
        int val;
        if (is_i32) val = ((const int*)mask)[b * S_ + i];
        else        val = mask[b * S_ + i];
        c += (val == 0) ? 1 : 0;
    }
    cnt[t] = c;
    __syncthreads();
    for (int s = 128; s > 0; s >>= 1) {
        if (t < s) cnt[t] += cnt[t + s];
        __syncthreads();
    }
    if (t == 0) lengths[b] = cnt[0];
}

// ---------------------------------------------------------------------------
// fp32 -> bf16, 4 per thread
// ---------------------------------------------------------------------------
__global__ __launch_bounds__(256) void tobf16_kernel(
    const float* __restrict__ in, u16* __restrict__ out) {
    size_t i = (size_t)blockIdx.x * 256 + threadIdx.x;
    float4 f = ((const float4*)in)[i];
    ushort4 o = { (u16)rne(f.x), (u16)rne(f.y), (u16)rne(f.z), (u16)rne(f.w) };
    ((ushort4*)out)[i] = o;
}

// ---------------------------------------------------------------------------
// transpose + bf16: W[K][N] fp32 -> WT[N][K] bf16
// ---------------------------------------------------------------------------
__global__ __launch_bounds__(256) void transpose_tobf16_kernel(
    const float* __restrict__ W, u16* __restrict__ T, int K, int N) {
    __shared__ float tl[32][33];
    const int t = threadIdx.x, tx = t & 31, ty = t >> 5;
    const int n0 = blockIdx.x * 32, k0 = blockIdx.y * 32;
#pragma unroll
    for (int i = 0; i < 4; ++i)
        tl[ty + i * 8][tx] = W[(size_t)(k0 + ty + i * 8) * N + n0 + tx];
    __syncthreads();
#pragma unroll
    for (int i = 0; i < 4; ++i) {
        float f = tl[tx][ty + i * 8];
        T[(size_t)(n0 + ty + i * 8) * K + k0 + tx] = (u16)rne(f);
    }
}

// ---------------------------------------------------------------------------
// R11: LDS-staged NT-GEMMs (flash-R10's proven global_load_lds + dbuf +
// XOR-swizzle pattern; measured 0 bank conflicts for this geometry).
// Swizzle: LDS 16B-seg within 64B row: stored segd = seg ^ ((row>>1)&3)
// (inverse-swizzled SOURCE address, linear LDS dest -- rule #21); frag
// read seg = g ^ ((c16>>1)&3).
// ---------------------------------------------------------------------------
#define GBK 32

// VT GEMM: C[b][d][tok] = sum_k wvt[d][k] * x[b][tok][k] + bv[d]
// BM=BN=128, 4 waves 2x2 (wave 64x64), grid (16, 8, B_).
__global__ __launch_bounds__(256, 2) void gemm_lds_vt(
    const u16* __restrict__ A,          // wvt [1024][1024]
    const u16* __restrict__ Bm,         // x_bf [8192][1024]
    const float* __restrict__ bias_row, // bv
    u16* __restrict__ C)                // vt [B][1024][2048]
{
    const int K = 1024, N = 2048;
    const int t = threadIdx.x, w = t >> 6, lane = t & 63;
    const int g = lane >> 4, c16 = lane & 15;
    const int m0 = blockIdx.y * 128;
    const int n0 = blockIdx.x * 128;
    const u16* Bb = Bm + (size_t)blockIdx.z * 2048 * 1024;
    u16* Cb = C + (size_t)blockIdx.z * 1024 * 2048;

    __shared__ alignas(16) u16 As[2][128 * GBK];   // 2 x 8KB
    __shared__ alignas(16) u16 Bs[2][128 * GBK];   // 2 x 8KB

    auto stage = [&](int buf, int k0) {
#pragma unroll
        for (int call = 0; call < 2; ++call) {
            const int slot = call * 256 + w * 64 + lane;
            const int row  = slot >> 2;
            const int segd = (slot & 3) ^ ((row >> 1) & 3);
            gload_lds16(A + (size_t)(m0 + row) * K + k0 + segd * 8,
                        &As[buf][(size_t)(call * 256 + w * 64) * 8]);
        }
#pragma unroll
        for (int call = 0; call < 2; ++call) {
            const int slot = call * 256 + w * 64 + lane;
            const int row  = slot >> 2;
            const int segd = (slot & 3) ^ ((row >> 1) & 3);
            gload_lds16(Bb + (size_t)(n0 + row) * K + k0 + segd * 8,
                        &Bs[buf][(size_t)(call * 256 + w * 64) * 8]);
        }
    };

    f32x4 acc[4][4];
#pragma unroll
    for (int i = 0; i < 4; ++i)
#pragma unroll
        for (int j = 0; j < 4; ++j) acc[i][j] = (f32x4){0.f, 0.f, 0.f, 0.f};

    const int rbase = (w >> 1) * 64;
    const int cbase = (w & 1) * 64;
    const int segr  = g ^ ((c16 >> 1) & 3);   // read swizzle (bases %16==0)

    stage(0, 0);
    __syncthreads();
    for (int ks = 0; ks < K / GBK; ++ks) {
        const int cur = ks & 1;
        if (ks + 1 < K / GBK) stage(cur ^ 1, (ks + 1) * GBK);
        bf16x8s a[4], b[4];
#pragma unroll
        for (int i = 0; i < 4; ++i)
            a[i] = *(const bf16x8s*)&As[cur][(rbase + i * 16 + c16) * GBK + segr * 8];
#pragma unroll
        for (int j = 0; j < 4; ++j)
            b[j] = *(const bf16x8s*)&Bs[cur][(cbase + j * 16 + c16) * GBK + segr * 8];
#pragma unroll
        for (int i = 0; i < 4; ++i)
#pragma unroll
            for (int j = 0; j < 4; ++j)
                acc[i][j] = MM(a[i], b[j], acc[i][j]);
        __syncthreads();   // drains prefetch vmcnt; cur reusable next+1
    }

#pragma unroll
    for (int i = 0; i < 4; ++i)
#pragma unroll
        for (int j = 0; j < 4; ++j) {
            const int n = n0 + cbase + j * 16 + c16;
#pragma unroll
            for (int r = 0; r < 4; ++r) {
                const int m = m0 + rbase + i * 16 + g * 4 + r;
                Cb[(size_t)m * N + n] = (u16)rne(acc[i][j][r] + bias_row[m]);
            }
        }
}

// Fused q/k GEMM: B = wqkt [256][1024] (rows 0-127 = Wq^T, 128-255 = Wk^T).
// BM=64 (A=x rows), BN=128, 4 waves 2x2 (wave 32x64), grid (2, 128).
// Epilogue: cols <128 -> qb (bias bq, *SCALE); cols >=128 -> kbuf (bias bk).
__global__ __launch_bounds__(256, 2) void gemm_lds_qk(
    const u16* __restrict__ A,          // x_bf [8192][1024]
    const u16* __restrict__ Bm,         // wqkt [256][1024]
    const float* __restrict__ bq, const float* __restrict__ bk,
    float scale, u16* __restrict__ qb, u16* __restrict__ kout)
{
    const int K = 1024;
    const int t = threadIdx.x, w = t >> 6, lane = t & 63;
    const int g = lane >> 4, c16 = lane & 15;
    const int m0 = blockIdx.y * 64;
    const int n0 = blockIdx.x * 128;

    __shared__ alignas(16) u16 As[2][64 * GBK];    // 2 x 4KB
    __shared__ alignas(16) u16 Bs[2][128 * GBK];   // 2 x 8KB

    auto stage = [&](int buf, int k0) {
        {
            const int slot = w * 64 + lane;        // 256 slots (A)
            const int row  = slot >> 2;
            const int segd = (slot & 3) ^ ((row >> 1) & 3);
            gload_lds16(A + (size_t)(m0 + row) * K + k0 + segd * 8,
                        &As[buf][(size_t)(w * 64) * 8]);
        }
#pragma unroll
        for (int call = 0; call < 2; ++call) {
            const int slot = call * 256 + w * 64 + lane;
            const int row  = slot >> 2;
            const int segd = (slot & 3) ^ ((row >> 1) & 3);
            gload_lds16(Bm + (size_t)(n0 + row) * K + k0 + segd * 8,
                        &Bs[buf][(size_t)(call * 256 + w * 64) * 8]);
        }
    };

    f32x4 acc[2][4];
#pragma unroll
    for (int i = 0; i < 2; ++i)
#pragma unroll
        for (int j = 0; j < 4; ++j) acc[i][j] = (f32x4){0.f, 0.f, 0.f, 0.f};

    const int rbase = (w >> 1) * 32;
    const int cbase = (w & 1) * 64;
    const int segr  = g ^ ((c16 >> 1) & 3);

    stage(0, 0);
    __syncthreads();
    for (int ks = 0; ks < K / GBK; ++ks) {
        const int cur = ks & 1;
        if (ks + 1 < K / GBK) stage(cur ^ 1, (ks + 1) * GBK);
        bf16x8s a[2], b[4];
#pragma unroll
        for (int i = 0; i < 2; ++i)
            a[i] = *(const bf16x8s*)&As[cur][(rbase + i * 16 + c16) * GBK + segr * 8];
#pragma unroll
        for (int j = 0; j < 4; ++j)
            b[j] = *(const bf16x8s*)&Bs[cur][(cbase + j * 16 + c16) * GBK + segr * 8];
#pragma unroll
        for (int i = 0; i < 2; ++i)
#pragma unroll
            for (int j = 0; j < 4; ++j)
                acc[i][j] = MM(a[i], b[j], acc[i][j]);
        __syncthreads();
    }

#pragma unroll
    for (int i = 0; i < 2; ++i)
#pragma unroll
        for (int j = 0; j < 4; ++j) {
            const int n = n0 + cbase + j * 16 + c16;
            const bool isq = (n < 128);
            const int nc = isq ? n : (n - 128);
            const float bc = isq ? bq[nc] : bk[nc];
            const float sc = isq ? scale : 1.0f;
#pragma unroll
            for (int r = 0; r < 4; ++r) {
                const int m = m0 + rbase + i * 16 + g * 4 + r;
                const float val = (acc[i][j][r] + bc) * sc;
                u16* dst = isq ? qb : kout;
                dst[(size_t)m * DK_ + nc] = (u16)rne(val);
            }
        }
}

// ---------------------------------------------------------------------------
// vsumf[b][d] = sum_s VT[b][d][s]   (one wave per row)
// ---------------------------------------------------------------------------
__global__ __launch_bounds__(64) void vsum_rows_kernel(
    const u16* __restrict__ vt, float* __restrict__ vsumf) {
    const int blk = blockIdx.x;            // b*1024 + d
    const int lane = threadIdx.x;
    const u16* rr = vt + (size_t)blk * S_;
    float s = 0.f;
    for (int ch = lane; ch < S_ / 8; ch += 64) {
        union { uint4 u; u16 e[8]; } a;
        a.u = ((const uint4*)rr)[ch];
#pragma unroll
        for (int j = 0; j < 8; ++j)
            s += __builtin_bit_cast(float, (u32)a.e[j] << 16);
    }
#pragma unroll
    for (int off = 1; off < 64; off <<= 1) s += __shfl_xor(s, off);
    if (lane == 0) vsumf[blk] = s;
}

// ---------------------------------------------------------------------------
// MFMA flash attention, bf16, LDS-STAGED (R10 structure, unchanged).
// 1024 blocks, XCD swizzle; 4 waves; block slice = 128 D-cols.
// Measured R10: 99us, 0 bank conflicts, MfmaUtil 10.3%.
// ---------------------------------------------------------------------------
#define KVB 32

__global__ __launch_bounds__(256, 3) void flash_mfma(
    const u16* __restrict__ qb, const u16* __restrict__ kbuf,
    const u16* __restrict__ vt, const float* __restrict__ vsumf,
    const int* __restrict__ lengths, float* __restrict__ out)
{
    const int lin     = (int)blockIdx.x;
    const int logical = (lin & 7) * 128 + (lin >> 3);
    const int tile    = 31 - (logical & 31);
    const int grp     = logical >> 5;
    const int b       = grp >> 3;
    const int slice   = grp & 7;

    const int r0 = tile * 64;
    const int t = threadIdx.x, w = t >> 6, lane = t & 63;
    const int g = lane >> 4, c16 = lane & 15;
    const int len = lengths[b];

    if (r0 >= len) {  // whole 64-row tile padded: rows = mean(v)
        const float inv = 1.0f / (float)S_;
        const float4* vs4 = (const float4*)(vsumf + (size_t)b * D_ + slice * 128);
        for (int idx = t; idx < 64 * 32; idx += 256) {  // 64 rows x 32 float4
            int rr = idx >> 5, c4 = idx & 31;
            float4 vv = vs4[c4];
            float4 o = { vv.x * inv, vv.y * inv, vv.z * inv, vv.w * inv };
            ((float4*)(out + ((size_t)(b * S_ + r0 + rr)) * D_ + slice * 128))[c4] = o;
        }
        return;
    }

    __shared__ alignas(16) u16 ksm[2][KVB * DK_];   // 2 x 8KB
    __shared__ alignas(16) u16 vsm[2][128 * KVB];   // 2 x 8KB

    const int qr = r0 + w * 16;       // wave's q-row base
    const int qg = qr + c16;          // this lane's softmax q row

    // Q B-fragments (hoisted)
    bf16x8s Q[4];
    {
        const size_t qrow = (size_t)(b * S_ + qr + c16) * DK_;
#pragma unroll
        for (int dt = 0; dt < 4; ++dt)
            Q[dt] = ldfrag(qb + qrow + dt * 32 + g * 8);
    }

    f32x4 acc[8];
#pragma unroll
    for (int i = 0; i < 8; ++i) acc[i] = (f32x4){0.f, 0.f, 0.f, 0.f};
    float m_r = -3.0e38f, l_r = 0.f;

    const int keyloc0 = ((c16 >> 2) << 3) + (c16 & 3);  // permuted key row
    const int kmax_w  = (qr >= len) ? -1 : min(qr + 15, len - 1);
    const int kmaxblk = min(r0 + 63, len - 1);          // block-uniform
    const int nt      = kmaxblk / KVB + 1;              // chunks (uniform)

    // ---- cooperative async stage of chunk kb2 into buffer bufi ----
    auto stage = [&](int bufi, int kb2) {
#pragma unroll
        for (int i = 0; i < 2; ++i) {              // K: 512 slots of 16B
            const int slot = i * 256 + w * 64 + lane;
            const int row  = slot >> 4;            // 0..31
            const int segd = (slot & 15) ^ ((row & 3) | (((row >> 3) & 3) << 2));
            const u16* gsrc = kbuf + (size_t)(b * S_ + kb2 + row) * DK_ + segd * 8;
            gload_lds16(gsrc, &ksm[bufi][(size_t)(i * 256 + w * 64) * 8]);
        }
#pragma unroll
        for (int i = 0; i < 2; ++i) {              // V: 512 slots of 16B
            const int slot = i * 256 + w * 64 + lane;
            const int row  = slot >> 2;            // 0..127
            const int segd = (slot & 3) ^ ((row >> 1) & 3);
            const u16* gsrc = vt + (size_t)(b * D_ + slice * 128 + row) * S_
                                 + kb2 + segd * 8;
            gload_lds16(gsrc, &vsm[bufi][(size_t)(i * 256 + w * 64) * 8]);
        }
    };

    stage(0, 0);
    __syncthreads();   // implicit vmcnt(0) drain completes stage 0

    for (int ti = 0; ti < nt; ++ti) {
        const int kb  = ti * KVB;
        const int cur = ti & 1;
        if (ti + 1 < nt) stage(cur ^ 1, kb + KVB);   // async prefetch next

        if (kb <= kmax_w) {
            // ---- S^T = K . Q^T from LDS (swizzled reads, 0-conflict) ----
            f32x4 sT[2];
#pragma unroll
            for (int kt = 0; kt < 2; ++kt) {
                f32x4 s = (f32x4){0.f, 0.f, 0.f, 0.f};
#pragma unroll
                for (int dt = 0; dt < 4; ++dt) {
                    const bf16x8s kf = *(const bf16x8s*)&ksm[cur]
                        [(keyloc0 + kt * 4) * DK_ + (((dt * 4 + g) ^ c16) * 8)];
                    s = MM(kf, Q[dt], s);
                }
                sT[kt] = s;
            }
            // ---- causal mask: reg r of tile kt = key kb + g*8 + kt*4 + r ----
#pragma unroll
            for (int kt = 0; kt < 2; ++kt)
#pragma unroll
                for (int r = 0; r < 4; ++r) {
                    int key = kb + g * 8 + kt * 4 + r;
                    if (key > qg) sT[kt][r] = -3.0e38f;
                }
            // ---- online softmax over key axis (per q row = lane c16) ----
            float cmax = sT[0][0];
#pragma unroll
            for (int r = 1; r < 4; ++r) cmax = fmaxf(cmax, sT[0][r]);
#pragma unroll
            for (int r = 0; r < 4; ++r) cmax = fmaxf(cmax, sT[1][r]);
            cmax = fmaxf(cmax, __shfl_xor(cmax, 16));
            cmax = fmaxf(cmax, __shfl_xor(cmax, 32));

            const bool noresc = __all(cmax <= m_r + 8.0f);  // defer-rescale T13
            float m_new = m_r, sc = 1.0f;
            if (!noresc) {
                m_new = fmaxf(m_r, cmax);
                sc = __expf(m_r - m_new);
            }

            float p[2][4];
            float rs = 0.f;
#pragma unroll
            for (int kt = 0; kt < 2; ++kt)
#pragma unroll
                for (int r = 0; r < 4; ++r) {
                    p[kt][r] = __expf(sT[kt][r] - m_new);
                    rs += p[kt][r];
                }
            rs += __shfl_xor(rs, 16);
            rs += __shfl_xor(rs, 32);

            if (!noresc) {
                // acc q rows are REG-indexed (row = g*4+r): per-row sc
                float scr0 = __shfl(sc, g * 4 + 0, 16);
                float scr1 = __shfl(sc, g * 4 + 1, 16);
                float scr2 = __shfl(sc, g * 4 + 2, 16);
                float scr3 = __shfl(sc, g * 4 + 3, 16);
                f32x4 scv = { scr0, scr1, scr2, scr3 };
#pragma unroll
                for (int i = 0; i < 8; ++i) acc[i] *= scv;
                l_r = l_r * sc + rs;
                m_r = m_new;
            } else {
                l_r += rs;
            }

            // ---- pack P into A-fragment octet (lane-local) ----
            union { u32 wrd[4]; bf16x8s v; } pa;
            pa.wrd[0] = pack2(p[0][0], p[0][1]);
            pa.wrd[1] = pack2(p[0][2], p[0][3]);
            pa.wrd[2] = pack2(p[1][0], p[1][1]);
            pa.wrd[3] = pack2(p[1][2], p[1][3]);

            // ---- PV from LDS (swizzled reads, 2-way = free) ----
#pragma unroll
            for (int cg = 0; cg < 8; ++cg) {
                const bf16x8s vf = *(const bf16x8s*)&vsm[cur]
                    [(cg * 16 + c16) * KVB + ((g ^ ((c16 >> 1) & 3)) * 8)];
                acc[cg] = MM(pa.v, vf, acc[cg]);
            }
        }

        __syncthreads();  // drains stage vmcnt; next buffer ready, cur free
    }

    // ---- epilogue: C rows = q (reg axis), cols = d (lane axis) ----
    const float linv = 1.0f / l_r;
    float iv[4];
    bool valid[4];
#pragma unroll
    for (int r = 0; r < 4; ++r) {
        const int row = g * 4 + r;
        iv[r] = __shfl(linv, row, 16);
        valid[r] = (qr + row) < len;
    }
    const float invS = 1.0f / (float)S_;
#pragma unroll
    for (int cg = 0; cg < 8; ++cg) {
        const int d = slice * 128 + cg * 16 + c16;
        const float vsv = vsumf[(size_t)b * D_ + d] * invS;
#pragma unroll
        for (int r = 0; r < 4; ++r) {
            const int rowg = qr + g * 4 + r;
            const float val = valid[r] ? acc[cg][r] * iv[r] : vsv;
            out[((size_t)(b * S_ + rowg)) * D_ + d] = val;
        }
    }
}

// ---------------------------------------------------------------------------
extern "C" void kernel_launch(void* const* d_in, const int* in_sizes, int n_in,
                              void* d_out, int out_size, void* d_ws, size_t ws_size,
                              hipStream_t stream) {
    const float*   x    = (const float*)d_in[0];
    const uint8_t* mask = (const uint8_t*)d_in[1];
    const float*   Wq   = (const float*)d_in[2];
    const float*   bq   = (const float*)d_in[3];
    const float*   Wk   = (const float*)d_in[4];
    const float*   bk   = (const float*)d_in[5];
    const float*   Wv   = (const float*)d_in[6];
    const float*   bv   = (const float*)d_in[7];
    float* out = (float*)d_out;

    // workspace (u16 planes), total ~40.4 MB
    u16* u = (u16*)d_ws;
    u16* x_bf = u;                    u += (size_t)8192 * 1024;
    u16* wqkt = u;                    u += (size_t)256 * 1024;  // rows 0-127 Wq^T, 128-255 Wk^T
    u16* wvt  = u;                    u += (size_t)1024 * 1024;
    u16* qb   = u;                    u += (size_t)8192 * 128;
    u16* kbuf = u;                    u += (size_t)8192 * 128;
    u16* vt   = u;                    u += (size_t)B_ * 1024 * 2048;
    float* vsumf = (float*)u;
    int* lengths = (int*)(vsumf + B_ * D_);

    const float SCALE = 0.08838834764831845f;  // 1/sqrt(128)

    lengths_kernel<<<dim3(B_), dim3(256), 0, stream>>>(mask, lengths);
    tobf16_kernel<<<dim3(8192), dim3(256), 0, stream>>>(x, x_bf);
    transpose_tobf16_kernel<<<dim3(4, 32), dim3(256), 0, stream>>>(Wq, wqkt, 1024, 128);
    transpose_tobf16_kernel<<<dim3(4, 32), dim3(256), 0, stream>>>(Wk, wqkt + (size_t)128 * 1024, 1024, 128);
    transpose_tobf16_kernel<<<dim3(32, 32), dim3(256), 0, stream>>>(Wv, wvt, 1024, 1024);

    // fused q/k projection (LDS-staged): q = (x@Wq+bq)*scale ; k = x@Wk+bk
    gemm_lds_qk<<<dim3(2, 128), dim3(256), 0, stream>>>(
        x_bf, wqkt, bq, bk, SCALE, qb, kbuf);
    // VT[b][d][tok] = Wv^T @ x[b]^T + bv[d]  (LDS-staged)
    gemm_lds_vt<<<dim3(16, 8, B_), dim3(256), 0, stream>>>(
        wvt, x_bf, bv, vt);

    vsum_rows_kernel<<<dim3(B_ * D_), dim3(64), 0, stream>>>(vt, vsumf);

    flash_mfma<<<dim3(1024), dim3(256), 0, stream>>>(
        qb, kbuf, vt, vsumf, lengths, out);
}